// Round 1
// baseline (3197.302 us; speedup 1.0000x reference)
//
#include <hip/hip_runtime.h>
#include <math.h>

#define BB 16
#define CC 128
#define LL 16000
#define KK 256
#define SS 3937
#define MM 4000
#define THRS 0.5f
#define STEP 0.1f   // float32(0.01/0.1) == 0.1f

// ---------------------------------------------------------------------------
// Strided conv1d (K=256, stride=4), fp32 register-tiled implicit GEMM.
// R14 VERBATIM (proven ~60us). Single fmaf chain per output, k ascending.
// [bit-path frozen] tx=s (coalesced epilogue), ty=c, W natural rows in LDS
// stride 68, double-buffered. x window in LDS.
// MODE 0: init. MODE 1: LCA update. MODE 2: final -> hardshrink to d_out.
// ---------------------------------------------------------------------------
template<int MODE>
__global__ __launch_bounds__(256, 2) void k_conv(
    const float* __restrict__ in0,     // x (MODE 0) or recon (MODE 1/2)
    const float* __restrict__ W,       // [C][K] natural
    float* __restrict__ drive,
    float* __restrict__ u)
{
    __shared__ __align__(16) float sW[2][128 * 68];  // 2 x 34.8 KB
    __shared__ __align__(16) float sX[768];
    __shared__ int sFlag;

    const int tid = threadIdx.x;
    const int tx = tid & 15;          // s-minor
    const int ty = tid >> 4;          // c-minor
    const int s0 = blockIdx.x * 128;
    const int b  = blockIdx.y;

    const int sc = tid >> 1;
    const int sg = (tid & 1) * 8;
    const float4* W4 = (const float4*)W;

    if (tid == 0) sFlag = 0;
    __syncthreads();

    bool nz = false;
    #pragma unroll
    for (int h = 0; h < 3; ++h) {
        int t = tid + 256 * h;
        int l = 4 * s0 + t;
        float v = (l < LL) ? in0[b * LL + l] : 0.f;
        sX[t] = v;
        nz |= (v != 0.f);
    }
    if (MODE != 0) { if (nz) atomicOr(&sFlag, 1); }
    __syncthreads();

    float acc[8][8];
    #pragma unroll
    for (int i = 0; i < 8; ++i)
        #pragma unroll
        for (int j = 0; j < 8; ++j) acc[i][j] = 0.f;

    const bool doit = (MODE == 0) || (sFlag != 0);   // block-uniform

    if (doit) {
        {
            float4* dst = (float4*)sW[0];
            #pragma unroll
            for (int w = 0; w < 8; ++w)
                dst[sc * 17 + sg + w] = W4[sc * 64 + sg + w];
        }
        __syncthreads();

        for (int kc = 0; kc < 4; ++kc) {         // k chunks ascending
            float4 pre[8];
            if (kc < 3) {
                #pragma unroll
                for (int w = 0; w < 8; ++w)
                    pre[w] = W4[sc * 64 + (kc + 1) * 16 + sg + w];
            }

            const float* wbuf = sW[kc & 1];
            const int xoff = 64 * kc;

            for (int kk4 = 0; kk4 < 16; ++kk4) {          // k ascending
                float4 xq[8];
                #pragma unroll
                for (int j = 0; j < 8; ++j)
                    xq[j] = *(const float4*)&sX[4 * (tx + 16 * j) + xoff + 4 * kk4];
                float4 w4[8];
                #pragma unroll
                for (int i = 0; i < 8; ++i)
                    w4[i] = *(const float4*)&wbuf[(ty + 16 * i) * 68 + 4 * kk4];
                #pragma unroll
                for (int dk = 0; dk < 4; ++dk) {
                    #pragma unroll
                    for (int i = 0; i < 8; ++i) {
                        float wv = (&w4[i].x)[dk];
                        #pragma unroll
                        for (int j = 0; j < 8; ++j)
                            acc[i][j] = fmaf(wv, (&xq[j].x)[dk], acc[i][j]);
                    }
                }
            }

            if (kc < 3) {
                float4* dst = (float4*)sW[(kc + 1) & 1];
                #pragma unroll
                for (int w = 0; w < 8; ++w)
                    dst[sc * 17 + sg + w] = pre[w];
            }
            __syncthreads();
        }
    }

    // epilogue: locked fp32 elementwise chain; s-contiguous stores
    #pragma unroll
    for (int j = 0; j < 8; ++j) {
        int s = s0 + tx + 16 * j;
        if (s < SS) {
            #pragma unroll
            for (int i = 0; i < 8; ++i) {
                int c = ty + 16 * i;
                size_t idx = (size_t)(b * CC + c) * SS + s;
                if (MODE == 0) {
                    float d = acc[i][j];
                    drive[idx] = d;
                    u[idx] = __fmul_rn(STEP, d);   // u1 = 0 + 0.1f*drive
                } else {
                    float uo = u[idx];
                    float dr = drive[idx];
                    float a  = (fabsf(uo) > THRS) ? uo : 0.f;
                    float t1 = __fsub_rn(dr, uo);
                    float t2 = __fsub_rn(t1, acc[i][j]);
                    float t3 = __fadd_rn(t2, a);
                    float t4 = __fmul_rn(STEP, t3);
                    float un = __fadd_rn(uo, t4);
                    if (MODE == 1) u[idx] = un;
                    else           u[idx] = (fabsf(un) > THRS) ? un : 0.f;  // final
                }
            }
        }
    }
}

// ---------------------------------------------------------------------------
// Transpose-conv (recon). Chain [bit-path frozen] identical to R5-R17:
//   recon[b][4m+r]: for c = 0..127 asc (4 stages x 32), q = 0..63 asc:
//       acc_r = fmaf(a[b][c][m-63+q], W[c][4*(63-q)+r], acc_r)
// R18: occupancy + scalar-weight rewrite.
//  - r-PAIR split across thread halves: threads 0..127 own r={0,1},
//    threads 128..255 own r={2,3} for the same 128-m tile. rp is
//    wave-uniform by construction (tid>>7). 2x thread count -> grid
//    (32,16) = 512 blocks -> 2 blocks/CU -> 2 waves/SIMD (was 1).
//  - Weight fetch moved off the VALU: W[c][4*(63-q)+rp..rp+1] is
//    wave-uniform; readfirstlane-forced index makes the float2 load a
//    scalar (s_load_dwordx2) candidate, and fmaf takes the SGPR operand
//    directly. Eliminates 256 v_readlane per channel per wave.
//  - Per-output fmaf chain order and operand values are IDENTICAL to R17
//    (c asc, q asc; zero-padded window; nz block skip) -> bitwise safe.
// ---------------------------------------------------------------------------
__global__ __launch_bounds__(256, 2) void k_recon(
    const float* __restrict__ u,
    const float* __restrict__ W,       // [C][K] natural layout
    float* __restrict__ recon)         // [B][LL]
{
    __shared__ __align__(16) float sA[32 * 192];   // 24.6 KB (stride 192)
    __shared__ int sFlag;

    const int tid = threadIdx.x;
    const int ml  = tid & 127;                                  // m_local
    const int rp  = __builtin_amdgcn_readfirstlane((tid >> 7) << 1); // 0 | 2
    const int m0  = blockIdx.x * 128;
    const int b   = blockIdx.y;
    const int m   = m0 + ml;

    if (tid == 0) sFlag = 0;
    __syncthreads();

    float acc0 = 0.f, acc1 = 0.f;

    for (int cs = 0; cs < 4; ++cs) {            // 32-channel stages, c ascending
        const int c0 = cs * 32;
        bool nz = false;
        #pragma unroll
        for (int h = 0; h < 24; ++h) {          // 24*256 = 32*192 elements
            int idx = tid + 256 * h;
            int cl  = idx / 192;
            int col = idx - cl * 192;
            int mm  = m0 - 63 + col;
            float v = 0.f;
            if (col < 191 && mm >= 0 && mm < SS) {
                float uu = u[(size_t)(b * CC + c0 + cl) * SS + mm];
                v = (fabsf(uu) > THRS) ? uu : 0.f;
            }
            sA[idx] = v;
            nz |= (v != 0.f);
        }
        if (nz) atomicOr(&sFlag, 1);
        __syncthreads();                        // staging + flags complete
        const int f = sFlag;                    // block-uniform read
        __syncthreads();                        // all threads have read f
        if (tid == 0) sFlag = 0;                // reset (ordered by loop-end barrier)

        if (f) {
            for (int cl = 0; cl < 32; ++cl) {   // c ascending
                const float* arow = sA + cl * 192 + ml;  // arow[q] = a[c][m-63+q]
                const float* wrow = W + (size_t)(c0 + cl) * KK;

                // pull the whole 64-tap a-window into registers first
                float av[64];
                #pragma unroll
                for (int t = 0; t < 64; ++t) av[t] = arow[t];

                #pragma unroll
                for (int q = 0; q < 64; ++q) {  // j = 63-q descending
                    float2 wq = *(const float2*)&wrow[4 * (63 - q) + rp];
                    acc0 = fmaf(av[q], wq.x, acc0);
                    acc1 = fmaf(av[q], wq.y, acc1);
                }
            }
        }
        __syncthreads();   // sA reads done + sFlag reset visible before next stage
    }

    if (m < MM) {
        float2* o = (float2*)(recon + (size_t)b * LL + 4 * m + rp);
        *o = make_float2(acc0, acc1);
    }
}

extern "C" void kernel_launch(void* const* d_in, const int* in_sizes, int n_in,
                              void* d_out, int out_size, void* d_ws, size_t ws_size,
                              hipStream_t stream) {
    const float* x = (const float*)d_in[0];   // [16][1][16000]
    const float* W = (const float*)d_in[1];   // [128][1][256]
    float* u = (float*)d_out;                 // u lives in d_out (fp32)

    float* ws    = (float*)d_ws;              // ~33.3 MB used
    float* drive = ws;                                    // 8062976
    float* recon = drive + (size_t)BB * CC * SS;          // 256000

    dim3 gConv(31, 16);   // ceil(3937/128) x B
    k_conv<0><<<gConv, 256, 0, stream>>>(x, W, drive, u);   // drive + u1

    for (int it = 0; it < 9; ++it) {   // iterations 2..10
        k_recon<<<dim3(32, 16), 256, 0, stream>>>(u, W, recon);
        if (it < 8)
            k_conv<1><<<gConv, 256, 0, stream>>>(recon, W, drive, u);
        else
            k_conv<2><<<gConv, 256, 0, stream>>>(recon, W, drive, u);  // final -> d_out
    }
}

// Round 2
// 3109.969 us; speedup vs baseline: 1.0281x; 1.0281x over previous
//
#include <hip/hip_runtime.h>
#include <math.h>

#define BB 16
#define CC 128
#define LL 16000
#define KK 256
#define SS 3937
#define MM 4000
#define THRS 0.5f
#define STEP 0.1f   // float32(0.01/0.1) == 0.1f

// ---------------------------------------------------------------------------
// Strided conv1d (K=256, stride=4), fp32 register-tiled implicit GEMM.
// R14 VERBATIM (proven ~60us). Single fmaf chain per output, k ascending.
// [bit-path frozen] tx=s (coalesced epilogue), ty=c, W natural rows in LDS
// stride 68, double-buffered. x window in LDS.
// MODE 0: init. MODE 1: LCA update. MODE 2: final -> hardshrink to d_out.
// ---------------------------------------------------------------------------
template<int MODE>
__global__ __launch_bounds__(256, 2) void k_conv(
    const float* __restrict__ in0,     // x (MODE 0) or recon (MODE 1/2)
    const float* __restrict__ W,       // [C][K] natural
    float* __restrict__ drive,
    float* __restrict__ u)
{
    __shared__ __align__(16) float sW[2][128 * 68];  // 2 x 34.8 KB
    __shared__ __align__(16) float sX[768];
    __shared__ int sFlag;

    const int tid = threadIdx.x;
    const int tx = tid & 15;          // s-minor
    const int ty = tid >> 4;          // c-minor
    const int s0 = blockIdx.x * 128;
    const int b  = blockIdx.y;

    const int sc = tid >> 1;
    const int sg = (tid & 1) * 8;
    const float4* W4 = (const float4*)W;

    if (tid == 0) sFlag = 0;
    __syncthreads();

    bool nz = false;
    #pragma unroll
    for (int h = 0; h < 3; ++h) {
        int t = tid + 256 * h;
        int l = 4 * s0 + t;
        float v = (l < LL) ? in0[b * LL + l] : 0.f;
        sX[t] = v;
        nz |= (v != 0.f);
    }
    if (MODE != 0) { if (nz) atomicOr(&sFlag, 1); }
    __syncthreads();

    float acc[8][8];
    #pragma unroll
    for (int i = 0; i < 8; ++i)
        #pragma unroll
        for (int j = 0; j < 8; ++j) acc[i][j] = 0.f;

    const bool doit = (MODE == 0) || (sFlag != 0);   // block-uniform

    if (doit) {
        {
            float4* dst = (float4*)sW[0];
            #pragma unroll
            for (int w = 0; w < 8; ++w)
                dst[sc * 17 + sg + w] = W4[sc * 64 + sg + w];
        }
        __syncthreads();

        for (int kc = 0; kc < 4; ++kc) {         // k chunks ascending
            float4 pre[8];
            if (kc < 3) {
                #pragma unroll
                for (int w = 0; w < 8; ++w)
                    pre[w] = W4[sc * 64 + (kc + 1) * 16 + sg + w];
            }

            const float* wbuf = sW[kc & 1];
            const int xoff = 64 * kc;

            for (int kk4 = 0; kk4 < 16; ++kk4) {          // k ascending
                float4 xq[8];
                #pragma unroll
                for (int j = 0; j < 8; ++j)
                    xq[j] = *(const float4*)&sX[4 * (tx + 16 * j) + xoff + 4 * kk4];
                float4 w4[8];
                #pragma unroll
                for (int i = 0; i < 8; ++i)
                    w4[i] = *(const float4*)&wbuf[(ty + 16 * i) * 68 + 4 * kk4];
                #pragma unroll
                for (int dk = 0; dk < 4; ++dk) {
                    #pragma unroll
                    for (int i = 0; i < 8; ++i) {
                        float wv = (&w4[i].x)[dk];
                        #pragma unroll
                        for (int j = 0; j < 8; ++j)
                            acc[i][j] = fmaf(wv, (&xq[j].x)[dk], acc[i][j]);
                    }
                }
            }

            if (kc < 3) {
                float4* dst = (float4*)sW[(kc + 1) & 1];
                #pragma unroll
                for (int w = 0; w < 8; ++w)
                    dst[sc * 17 + sg + w] = pre[w];
            }
            __syncthreads();
        }
    }

    // epilogue: locked fp32 elementwise chain; s-contiguous stores
    #pragma unroll
    for (int j = 0; j < 8; ++j) {
        int s = s0 + tx + 16 * j;
        if (s < SS) {
            #pragma unroll
            for (int i = 0; i < 8; ++i) {
                int c = ty + 16 * i;
                size_t idx = (size_t)(b * CC + c) * SS + s;
                if (MODE == 0) {
                    float d = acc[i][j];
                    drive[idx] = d;
                    u[idx] = __fmul_rn(STEP, d);   // u1 = 0 + 0.1f*drive
                } else {
                    float uo = u[idx];
                    float dr = drive[idx];
                    float a  = (fabsf(uo) > THRS) ? uo : 0.f;
                    float t1 = __fsub_rn(dr, uo);
                    float t2 = __fsub_rn(t1, acc[i][j]);
                    float t3 = __fadd_rn(t2, a);
                    float t4 = __fmul_rn(STEP, t3);
                    float un = __fadd_rn(uo, t4);
                    if (MODE == 1) u[idx] = un;
                    else           u[idx] = (fabsf(un) > THRS) ? un : 0.f;  // final
                }
            }
        }
    }
}

// ---------------------------------------------------------------------------
// Transpose-conv (recon). Chain [bit-path frozen] identical to R5-R18:
//   recon[b][4m+r]: for c = 0..127 asc (4 stages x 32), q = 0..63 asc:
//       acc_r = fmaf(a[b][c][m-63+q], W[c][4*(63-q)+r], acc_r)
// R19: latency-stall fix (R18 post-mortem: VALUBusy 10.6%, VGPR 76 ->
// av[64] register array starved the load pipeliner).
//  - Back to 4 chains/thread (256 fmaf per 64 a-reads: best issue ratio;
//    4 interleaved chains self-hide fmaf latency in one wave).
//  - a read per-q straight from LDS (ds_read_b32, const offset) -- no
//    register array; frees ~60 VGPRs for deep load pipelining.
//  - Weight as per-lane-uniform float4 VMEM load (W + c*256 + 252-4q,
//    64 const-offset loads/channel): coalesces to one 16B L1-hit per
//    inst, rides vmcnt (decoupled from the ds_read lgkmcnt stream),
//    1 issue slot instead of 4 readlanes. W = 128KB, cache-hot.
//  - T14 async-stage: next stage's 40 u-values prefetched into regs
//    before compute (sched_barrier pins issue), ds_write after.
//  - launch_bounds(256,1): grid (16,16) is 1 block/CU anyway; uncap VGPR.
// ---------------------------------------------------------------------------
__global__ __launch_bounds__(256, 1) void k_recon(
    const float* __restrict__ u,
    const float* __restrict__ W,       // [C][K] natural layout
    float* __restrict__ recon)         // [B][LL]
{
    __shared__ __align__(16) float sA[32 * 320];   // 40.96 KB (stride 320)
    __shared__ int sFlag;

    const int tid = threadIdx.x;      // = m_local in [0,256)
    const int m0 = blockIdx.x * 256;
    const int b  = blockIdx.y;
    const int m  = m0 + tid;

    if (tid == 0) sFlag = 0;
    __syncthreads();

    float pv[40];   // per-thread slice of one 32x320 stage (static-indexed)

    // ---- load stage 0 into regs ----
    #pragma unroll
    for (int h = 0; h < 40; ++h) {
        int idx = tid + 256 * h;
        int cl  = idx / 320;
        int col = idx - cl * 320;
        int mm  = m0 - 63 + col;
        float v = 0.f;
        if (col < 319 && mm >= 0 && mm < SS) {
            float uu = u[(size_t)(b * CC + cl) * SS + mm];
            v = (fabsf(uu) > THRS) ? uu : 0.f;
        }
        pv[h] = v;
    }
    {
        bool nz = false;
        #pragma unroll
        for (int h = 0; h < 40; ++h) {
            sA[tid + 256 * h] = pv[h];
            nz |= (pv[h] != 0.f);
        }
        if (nz) atomicOr(&sFlag, 1);
    }
    __syncthreads();

    float acc0 = 0.f, acc1 = 0.f, acc2 = 0.f, acc3 = 0.f;

    for (int cs = 0; cs < 4; ++cs) {            // 32-channel stages, c ascending
        const int f = sFlag;                    // block-uniform read
        __syncthreads();                        // all threads have read f
        if (tid == 0) sFlag = 0;                // reset (visible by post-compute barrier)

        // ---- issue next stage's global loads early (hide under compute) ----
        if (cs < 3) {
            const int c0n = (cs + 1) * 32;
            #pragma unroll
            for (int h = 0; h < 40; ++h) {
                int idx = tid + 256 * h;
                int cl  = idx / 320;
                int col = idx - cl * 320;
                int mm  = m0 - 63 + col;
                float v = 0.f;
                if (col < 319 && mm >= 0 && mm < SS) {
                    float uu = u[(size_t)(b * CC + c0n + cl) * SS + mm];
                    v = (fabsf(uu) > THRS) ? uu : 0.f;
                }
                pv[h] = v;
            }
            __builtin_amdgcn_sched_barrier(0);  // keep load issue ahead of compute
        }

        if (f) {
            const int c0 = cs * 32;
            for (int cl = 0; cl < 32; ++cl) {   // c ascending
                const float* arow = sA + cl * 320 + tid;     // arow[q] = a[c][m-63+q]
                const float* wrow = W + (size_t)(c0 + cl) * KK;
                #pragma unroll
                for (int q = 0; q < 64; ++q) {  // j = 63-q descending
                    float4 w = *(const float4*)&wrow[4 * (63 - q)];  // lane-uniform 16B
                    float a  = arow[q];                               // ds_read_b32
                    acc0 = fmaf(a, w.x, acc0);
                    acc1 = fmaf(a, w.y, acc1);
                    acc2 = fmaf(a, w.z, acc2);
                    acc3 = fmaf(a, w.w, acc3);
                }
            }
        }
        __syncthreads();   // sA reads done + sFlag reset visible

        if (cs < 3) {
            bool nz = false;
            #pragma unroll
            for (int h = 0; h < 40; ++h) {
                sA[tid + 256 * h] = pv[h];
                nz |= (pv[h] != 0.f);
            }
            if (nz) atomicOr(&sFlag, 1);
        }
        __syncthreads();   // staging visible before next stage's flag read
    }

    if (m < MM) {
        float4* o = (float4*)(recon + (size_t)b * LL + 4 * m);
        *o = make_float4(acc0, acc1, acc2, acc3);
    }
}

extern "C" void kernel_launch(void* const* d_in, const int* in_sizes, int n_in,
                              void* d_out, int out_size, void* d_ws, size_t ws_size,
                              hipStream_t stream) {
    const float* x = (const float*)d_in[0];   // [16][1][16000]
    const float* W = (const float*)d_in[1];   // [128][1][256]
    float* u = (float*)d_out;                 // u lives in d_out (fp32)

    float* ws    = (float*)d_ws;              // ~33.3 MB used
    float* drive = ws;                                    // 8062976
    float* recon = drive + (size_t)BB * CC * SS;          // 256000

    dim3 gConv(31, 16);   // ceil(3937/128) x B
    k_conv<0><<<gConv, 256, 0, stream>>>(x, W, drive, u);   // drive + u1

    for (int it = 0; it < 9; ++it) {   // iterations 2..10
        k_recon<<<dim3(16, 16), 256, 0, stream>>>(u, W, recon);
        if (it < 8)
            k_conv<1><<<gConv, 256, 0, stream>>>(recon, W, drive, u);
        else
            k_conv<2><<<gConv, 256, 0, stream>>>(recon, W, drive, u);  // final -> d_out
    }
}

// Round 3
// 2247.566 us; speedup vs baseline: 1.4226x; 1.3837x over previous
//
#include <hip/hip_runtime.h>
#include <math.h>

#define BB 16
#define CC 128
#define LL 16000
#define KK 256
#define SS 3937
#define MM 4000
#define THRS 0.5f
#define STEP 0.1f   // float32(0.01/0.1) == 0.1f

// ---------------------------------------------------------------------------
// Strided conv1d (K=256, stride=4), fp32 register-tiled implicit GEMM.
// R14 VERBATIM (proven ~60us). Single fmaf chain per output, k ascending.
// [bit-path frozen] tx=s (coalesced epilogue), ty=c, W natural rows in LDS
// stride 68, double-buffered. x window in LDS.
// MODE 0: init. MODE 1: LCA update. MODE 2: final -> hardshrink to d_out.
// ---------------------------------------------------------------------------
template<int MODE>
__global__ __launch_bounds__(256, 2) void k_conv(
    const float* __restrict__ in0,     // x (MODE 0) or recon (MODE 1/2)
    const float* __restrict__ W,       // [C][K] natural
    float* __restrict__ drive,
    float* __restrict__ u)
{
    __shared__ __align__(16) float sW[2][128 * 68];  // 2 x 34.8 KB
    __shared__ __align__(16) float sX[768];
    __shared__ int sFlag;

    const int tid = threadIdx.x;
    const int tx = tid & 15;          // s-minor
    const int ty = tid >> 4;          // c-minor
    const int s0 = blockIdx.x * 128;
    const int b  = blockIdx.y;

    const int sc = tid >> 1;
    const int sg = (tid & 1) * 8;
    const float4* W4 = (const float4*)W;

    if (tid == 0) sFlag = 0;
    __syncthreads();

    bool nz = false;
    #pragma unroll
    for (int h = 0; h < 3; ++h) {
        int t = tid + 256 * h;
        int l = 4 * s0 + t;
        float v = (l < LL) ? in0[b * LL + l] : 0.f;
        sX[t] = v;
        nz |= (v != 0.f);
    }
    if (MODE != 0) { if (nz) atomicOr(&sFlag, 1); }
    __syncthreads();

    float acc[8][8];
    #pragma unroll
    for (int i = 0; i < 8; ++i)
        #pragma unroll
        for (int j = 0; j < 8; ++j) acc[i][j] = 0.f;

    const bool doit = (MODE == 0) || (sFlag != 0);   // block-uniform

    if (doit) {
        {
            float4* dst = (float4*)sW[0];
            #pragma unroll
            for (int w = 0; w < 8; ++w)
                dst[sc * 17 + sg + w] = W4[sc * 64 + sg + w];
        }
        __syncthreads();

        for (int kc = 0; kc < 4; ++kc) {         // k chunks ascending
            float4 pre[8];
            if (kc < 3) {
                #pragma unroll
                for (int w = 0; w < 8; ++w)
                    pre[w] = W4[sc * 64 + (kc + 1) * 16 + sg + w];
            }

            const float* wbuf = sW[kc & 1];
            const int xoff = 64 * kc;

            for (int kk4 = 0; kk4 < 16; ++kk4) {          // k ascending
                float4 xq[8];
                #pragma unroll
                for (int j = 0; j < 8; ++j)
                    xq[j] = *(const float4*)&sX[4 * (tx + 16 * j) + xoff + 4 * kk4];
                float4 w4[8];
                #pragma unroll
                for (int i = 0; i < 8; ++i)
                    w4[i] = *(const float4*)&wbuf[(ty + 16 * i) * 68 + 4 * kk4];
                #pragma unroll
                for (int dk = 0; dk < 4; ++dk) {
                    #pragma unroll
                    for (int i = 0; i < 8; ++i) {
                        float wv = (&w4[i].x)[dk];
                        #pragma unroll
                        for (int j = 0; j < 8; ++j)
                            acc[i][j] = fmaf(wv, (&xq[j].x)[dk], acc[i][j]);
                    }
                }
            }

            if (kc < 3) {
                float4* dst = (float4*)sW[(kc + 1) & 1];
                #pragma unroll
                for (int w = 0; w < 8; ++w)
                    dst[sc * 17 + sg + w] = pre[w];
            }
            __syncthreads();
        }
    }

    // epilogue: locked fp32 elementwise chain; s-contiguous stores
    #pragma unroll
    for (int j = 0; j < 8; ++j) {
        int s = s0 + tx + 16 * j;
        if (s < SS) {
            #pragma unroll
            for (int i = 0; i < 8; ++i) {
                int c = ty + 16 * i;
                size_t idx = (size_t)(b * CC + c) * SS + s;
                if (MODE == 0) {
                    float d = acc[i][j];
                    drive[idx] = d;
                    u[idx] = __fmul_rn(STEP, d);   // u1 = 0 + 0.1f*drive
                } else {
                    float uo = u[idx];
                    float dr = drive[idx];
                    float a  = (fabsf(uo) > THRS) ? uo : 0.f;
                    float t1 = __fsub_rn(dr, uo);
                    float t2 = __fsub_rn(t1, acc[i][j]);
                    float t3 = __fadd_rn(t2, a);
                    float t4 = __fmul_rn(STEP, t3);
                    float un = __fadd_rn(uo, t4);
                    if (MODE == 1) u[idx] = un;
                    else           u[idx] = (fabsf(un) > THRS) ? un : 0.f;  // final
                }
            }
        }
    }
}

// ---------------------------------------------------------------------------
// Transpose-conv (recon). Chain [bit-path frozen] identical to R5-R19:
//   recon[b][4m+r]: for c = 0..127 asc (4 stages x 32), q = 0..63 asc:
//       acc_r = fmaf(a[b][c][m-63+q], W[c][4*(63-q)+r], acc_r)
// R20: all-LDS inner loop (R19 post-mortem: per-q VMEM w-loads were
// latency-bound at ~13 cyc/load with VGPRs strangled by the pv[40]
// prefetch; occupancy is structurally 1 wave/SIMD -> single-wave issue
// efficiency is everything).
//  - W rows staged into LDS per stage (32 KB): inner q reads w as ONE
//    ds_read_b128 at a wave-uniform address (broadcast, conflict-free).
//  - a read per-q: ds_read_b32, consecutive lanes (2-way alias = free).
//  - 128 independent LDS ops per channel, all compile-time offsets ->
//    compiler pipelines with fine-grained lgkmcnt.
//  - pv[40] prefetch DROPPED: frees 40 VGPRs; staging bubble ~0.4us/stage.
// ---------------------------------------------------------------------------
__global__ __launch_bounds__(256, 1) void k_recon(
    const float* __restrict__ u,
    const float* __restrict__ W,       // [C][K] natural layout
    float* __restrict__ recon)         // [B][LL]
{
    __shared__ __align__(16) float sA[32 * 320];   // 40.96 KB (stride 320)
    __shared__ __align__(16) float sW[32 * 256];   // 32 KB
    __shared__ int sFlag;

    const int tid = threadIdx.x;      // = m_local in [0,256)
    const int m0 = blockIdx.x * 256;
    const int b  = blockIdx.y;
    const int m  = m0 + tid;

    if (tid == 0) sFlag = 0;
    __syncthreads();

    float acc0 = 0.f, acc1 = 0.f, acc2 = 0.f, acc3 = 0.f;

    for (int cs = 0; cs < 4; ++cs) {            // 32-channel stages, c ascending
        const int c0 = cs * 32;

        // ---- stage a-tile (hardshrink at write; nz flag) ----
        bool nz = false;
        #pragma unroll
        for (int h = 0; h < 40; ++h) {
            int idx = tid + 256 * h;
            int cl  = idx / 320;
            int col = idx - cl * 320;
            int mm  = m0 - 63 + col;
            float v = 0.f;
            if (col < 319 && mm >= 0 && mm < SS) {
                float uu = u[(size_t)(b * CC + c0 + cl) * SS + mm];
                v = (fabsf(uu) > THRS) ? uu : 0.f;
            }
            sA[idx] = v;
            nz |= (v != 0.f);
        }
        if (nz) atomicOr(&sFlag, 1);

        // ---- stage W rows (natural layout, fully coalesced f4) ----
        {
            const float4* Wg = (const float4*)(W + (size_t)c0 * KK);
            float4* sW4 = (float4*)sW;
            #pragma unroll
            for (int h = 0; h < 8; ++h)
                sW4[tid + 256 * h] = Wg[tid + 256 * h];
        }

        __syncthreads();                        // staging + flags complete
        const int f = sFlag;                    // block-uniform read
        __syncthreads();                        // all threads have read f
        if (tid == 0) sFlag = 0;                // reset (ordered by loop-end barrier)

        if (f) {
            for (int cl = 0; cl < 32; ++cl) {   // c ascending
                const float* arow = sA + cl * 320 + tid;          // arow[q] = a[c][m-63+q]
                const float4* wrow4 = (const float4*)(sW + cl * 256);
                #pragma unroll
                for (int q = 0; q < 64; ++q) {  // j = 63-q descending
                    float4 w = wrow4[63 - q];   // broadcast ds_read_b128
                    float a  = arow[q];         // ds_read_b32, 2-way alias (free)
                    acc0 = fmaf(a, w.x, acc0);
                    acc1 = fmaf(a, w.y, acc1);
                    acc2 = fmaf(a, w.z, acc2);
                    acc3 = fmaf(a, w.w, acc3);
                }
            }
        }
        __syncthreads();   // sA/sW reads done + sFlag reset visible before next stage
    }

    if (m < MM) {
        float4* o = (float4*)(recon + (size_t)b * LL + 4 * m);
        *o = make_float4(acc0, acc1, acc2, acc3);
    }
}

extern "C" void kernel_launch(void* const* d_in, const int* in_sizes, int n_in,
                              void* d_out, int out_size, void* d_ws, size_t ws_size,
                              hipStream_t stream) {
    const float* x = (const float*)d_in[0];   // [16][1][16000]
    const float* W = (const float*)d_in[1];   // [128][1][256]
    float* u = (float*)d_out;                 // u lives in d_out (fp32)

    float* ws    = (float*)d_ws;              // ~33.3 MB used
    float* drive = ws;                                    // 8062976
    float* recon = drive + (size_t)BB * CC * SS;          // 256000

    dim3 gConv(31, 16);   // ceil(3937/128) x B
    k_conv<0><<<gConv, 256, 0, stream>>>(x, W, drive, u);   // drive + u1

    for (int it = 0; it < 9; ++it) {   // iterations 2..10
        k_recon<<<dim3(16, 16), 256, 0, stream>>>(u, W, recon);
        if (it < 8)
            k_conv<1><<<gConv, 256, 0, stream>>>(recon, W, drive, u);
        else
            k_conv<2><<<gConv, 256, 0, stream>>>(recon, W, drive, u);  // final -> d_out
    }
}

// Round 4
// 2187.051 us; speedup vs baseline: 1.4619x; 1.0277x over previous
//
#include <hip/hip_runtime.h>
#include <math.h>

#define BB 16
#define CC 128
#define LL 16000
#define KK 256
#define SS 3937
#define MM 4000
#define THRS 0.5f
#define STEP 0.1f   // float32(0.01/0.1) == 0.1f

// ---------------------------------------------------------------------------
// Strided conv1d (K=256, stride=4), fp32 register-tiled implicit GEMM.
// R14 VERBATIM (proven ~60us). Single fmaf chain per output, k ascending.
// [bit-path frozen] tx=s (coalesced epilogue), ty=c, W natural rows in LDS
// stride 68, double-buffered. x window in LDS.
// MODE 0: init. MODE 1: LCA update. MODE 2: final -> hardshrink to d_out.
// ---------------------------------------------------------------------------
template<int MODE>
__global__ __launch_bounds__(256, 2) void k_conv(
    const float* __restrict__ in0,     // x (MODE 0) or recon (MODE 1/2)
    const float* __restrict__ W,       // [C][K] natural
    float* __restrict__ drive,
    float* __restrict__ u)
{
    __shared__ __align__(16) float sW[2][128 * 68];  // 2 x 34.8 KB
    __shared__ __align__(16) float sX[768];
    __shared__ int sFlag;

    const int tid = threadIdx.x;
    const int tx = tid & 15;          // s-minor
    const int ty = tid >> 4;          // c-minor
    const int s0 = blockIdx.x * 128;
    const int b  = blockIdx.y;

    const int sc = tid >> 1;
    const int sg = (tid & 1) * 8;
    const float4* W4 = (const float4*)W;

    if (tid == 0) sFlag = 0;
    __syncthreads();

    bool nz = false;
    #pragma unroll
    for (int h = 0; h < 3; ++h) {
        int t = tid + 256 * h;
        int l = 4 * s0 + t;
        float v = (l < LL) ? in0[b * LL + l] : 0.f;
        sX[t] = v;
        nz |= (v != 0.f);
    }
    if (MODE != 0) { if (nz) atomicOr(&sFlag, 1); }
    __syncthreads();

    float acc[8][8];
    #pragma unroll
    for (int i = 0; i < 8; ++i)
        #pragma unroll
        for (int j = 0; j < 8; ++j) acc[i][j] = 0.f;

    const bool doit = (MODE == 0) || (sFlag != 0);   // block-uniform

    if (doit) {
        {
            float4* dst = (float4*)sW[0];
            #pragma unroll
            for (int w = 0; w < 8; ++w)
                dst[sc * 17 + sg + w] = W4[sc * 64 + sg + w];
        }
        __syncthreads();

        for (int kc = 0; kc < 4; ++kc) {         // k chunks ascending
            float4 pre[8];
            if (kc < 3) {
                #pragma unroll
                for (int w = 0; w < 8; ++w)
                    pre[w] = W4[sc * 64 + (kc + 1) * 16 + sg + w];
            }

            const float* wbuf = sW[kc & 1];
            const int xoff = 64 * kc;

            for (int kk4 = 0; kk4 < 16; ++kk4) {          // k ascending
                float4 xq[8];
                #pragma unroll
                for (int j = 0; j < 8; ++j)
                    xq[j] = *(const float4*)&sX[4 * (tx + 16 * j) + xoff + 4 * kk4];
                float4 w4[8];
                #pragma unroll
                for (int i = 0; i < 8; ++i)
                    w4[i] = *(const float4*)&wbuf[(ty + 16 * i) * 68 + 4 * kk4];
                #pragma unroll
                for (int dk = 0; dk < 4; ++dk) {
                    #pragma unroll
                    for (int i = 0; i < 8; ++i) {
                        float wv = (&w4[i].x)[dk];
                        #pragma unroll
                        for (int j = 0; j < 8; ++j)
                            acc[i][j] = fmaf(wv, (&xq[j].x)[dk], acc[i][j]);
                    }
                }
            }

            if (kc < 3) {
                float4* dst = (float4*)sW[(kc + 1) & 1];
                #pragma unroll
                for (int w = 0; w < 8; ++w)
                    dst[sc * 17 + sg + w] = pre[w];
            }
            __syncthreads();
        }
    }

    // epilogue: locked fp32 elementwise chain; s-contiguous stores
    #pragma unroll
    for (int j = 0; j < 8; ++j) {
        int s = s0 + tx + 16 * j;
        if (s < SS) {
            #pragma unroll
            for (int i = 0; i < 8; ++i) {
                int c = ty + 16 * i;
                size_t idx = (size_t)(b * CC + c) * SS + s;
                if (MODE == 0) {
                    float d = acc[i][j];
                    drive[idx] = d;
                    u[idx] = __fmul_rn(STEP, d);   // u1 = 0 + 0.1f*drive
                } else {
                    float uo = u[idx];
                    float dr = drive[idx];
                    float a  = (fabsf(uo) > THRS) ? uo : 0.f;
                    float t1 = __fsub_rn(dr, uo);
                    float t2 = __fsub_rn(t1, acc[i][j]);
                    float t3 = __fadd_rn(t2, a);
                    float t4 = __fmul_rn(STEP, t3);
                    float un = __fadd_rn(uo, t4);
                    if (MODE == 1) u[idx] = un;
                    else           u[idx] = (fabsf(un) > THRS) ? un : 0.f;  // final
                }
            }
        }
    }
}

// ---------------------------------------------------------------------------
// float readlane via int builtin (lane is compile-time constant here)
// ---------------------------------------------------------------------------
__device__ __forceinline__ float rdlane_f(float v, int lane) {
    union { float f; int i; } x;
    x.f = v;
    x.i = __builtin_amdgcn_readlane(x.i, lane);
    return x.f;
}

// ---------------------------------------------------------------------------
// Transpose-conv (recon). Chain [bit-path frozen] identical to R5-R20:
//   recon[b][4m+r]: for c = 0..127 asc (4 stages x 32), q = 0..63 asc:
//       acc_r = fmaf(a[b][c][m-63+q], W[c][4*(63-q)+r], acc_r)
// R21: LDS-pipe decongestion (R20 post-mortem: 4 waves x 128 LDS ops per
// channel on the ONE shared per-CU LDS pipe ~= 2-3k cyc/ch/CU -> the wall;
// VALU only needed 512 cyc/SIMD/ch, VALUBusy 16.7%).
//  - w distribution moved OFF the LDS pipe onto the 4 independent VALU
//    pipes: per channel each lane loads float4 wv = Wrow4[lane] (one
//    coalesced 1024B global load per wave, L2-hot, double-buffered to
//    next channel -> latency hidden under compute). Per q, wrow4[63-q]
//    is lane (63-q)'s register: 4 compile-time v_readlane -> SGPRs,
//    v_fma_f32 takes the SGPR operand (1 sgpr read/VALU op, legal).
//  - LDS traffic: only the a-reads remain (64 b32/ch/wave; adjacent q
//    merge into ds_read2_b32). 128 -> ~33 LDS instr per channel per wave.
//  - sW dropped entirely (LDS 74 -> 41 KB; no W staging, fewer barriers).
//  - Unlike old R17 (same readlane idea, 200us): NO av[64] register
//    block (per-q ds_read2 interleaves with the 8-VALU q-body under
//    fine-grained lgkmcnt, ~80 free VGPRs of scheduler lookahead).
// ---------------------------------------------------------------------------
__global__ __launch_bounds__(256, 1) void k_recon(
    const float* __restrict__ u,
    const float* __restrict__ W,       // [C][K] natural layout
    float* __restrict__ recon)         // [B][LL]
{
    __shared__ __align__(16) float sA[32 * 320];   // 40.96 KB (stride 320)
    __shared__ int sFlag;

    const int tid  = threadIdx.x;      // = m_local in [0,256)
    const int lane = tid & 63;
    const int m0 = blockIdx.x * 256;
    const int b  = blockIdx.y;
    const int m  = m0 + tid;

    if (tid == 0) sFlag = 0;
    __syncthreads();

    float acc0 = 0.f, acc1 = 0.f, acc2 = 0.f, acc3 = 0.f;

    for (int cs = 0; cs < 4; ++cs) {            // 32-channel stages, c ascending
        const int c0 = cs * 32;

        // ---- stage a-tile (hardshrink at write; nz flag) ----
        bool nz = false;
        #pragma unroll
        for (int h = 0; h < 40; ++h) {
            int idx = tid + 256 * h;
            int cl  = idx / 320;
            int col = idx - cl * 320;
            int mm  = m0 - 63 + col;
            float v = 0.f;
            if (col < 319 && mm >= 0 && mm < SS) {
                float uu = u[(size_t)(b * CC + c0 + cl) * SS + mm];
                v = (fabsf(uu) > THRS) ? uu : 0.f;
            }
            sA[idx] = v;
            nz |= (v != 0.f);
        }
        if (nz) atomicOr(&sFlag, 1);

        __syncthreads();                        // staging + flags complete
        const int f = sFlag;                    // block-uniform read
        __syncthreads();                        // all threads have read f
        if (tid == 0) sFlag = 0;                // reset (ordered by loop-end barrier)

        if (f) {
            const float4* Wg4 = (const float4*)(W + (size_t)c0 * KK);
            float4 wcur = Wg4[lane];            // cl = 0 row, cooperative
            for (int cl = 0; cl < 32; ++cl) {   // c ascending
                float4 wnxt;
                if (cl < 31) wnxt = Wg4[(cl + 1) * 64 + lane];  // prefetch next row

                const float* arow = sA + cl * 320 + tid;  // arow[q] = a[c][m-63+q]
                #pragma unroll
                for (int q = 0; q < 64; ++q) {  // j = 63-q descending
                    float a  = arow[q];         // ds_read (pairs -> ds_read2_b32)
                    float wx = rdlane_f(wcur.x, 63 - q);
                    float wy = rdlane_f(wcur.y, 63 - q);
                    float wz = rdlane_f(wcur.z, 63 - q);
                    float ww = rdlane_f(wcur.w, 63 - q);
                    acc0 = fmaf(a, wx, acc0);
                    acc1 = fmaf(a, wy, acc1);
                    acc2 = fmaf(a, wz, acc2);
                    acc3 = fmaf(a, ww, acc3);
                }
                wcur = wnxt;
            }
        }
        __syncthreads();   // sA reads done + sFlag reset visible before next stage
    }

    if (m < MM) {
        float4* o = (float4*)(recon + (size_t)b * LL + 4 * m);
        *o = make_float4(acc0, acc1, acc2, acc3);
    }
}

extern "C" void kernel_launch(void* const* d_in, const int* in_sizes, int n_in,
                              void* d_out, int out_size, void* d_ws, size_t ws_size,
                              hipStream_t stream) {
    const float* x = (const float*)d_in[0];   // [16][1][16000]
    const float* W = (const float*)d_in[1];   // [128][1][256]
    float* u = (float*)d_out;                 // u lives in d_out (fp32)

    float* ws    = (float*)d_ws;              // ~33.3 MB used
    float* drive = ws;                                    // 8062976
    float* recon = drive + (size_t)BB * CC * SS;          // 256000

    dim3 gConv(31, 16);   // ceil(3937/128) x B
    k_conv<0><<<gConv, 256, 0, stream>>>(x, W, drive, u);   // drive + u1

    for (int it = 0; it < 9; ++it) {   // iterations 2..10
        k_recon<<<dim3(16, 16), 256, 0, stream>>>(u, W, recon);
        if (it < 8)
            k_conv<1><<<gConv, 256, 0, stream>>>(recon, W, drive, u);
        else
            k_conv<2><<<gConv, 256, 0, stream>>>(recon, W, drive, u);  // final -> d_out
    }
}